// Round 1
// baseline (1245.468 us; speedup 1.0000x reference)
//
#include <hip/hip_runtime.h>
#include <hip/hip_bf16.h>

// SimpleMoE: B=2,S=2048 -> 4096 tokens, DIM=1024, FF=4096, E=8, top-2 routing.
// Strategy: gate (fp64) -> per-expert pair buckets -> grouped GEMM1 (x@W1,relu)
// -> H (bf16 in ws) -> grouped GEMM2 (H@W2), weighted atomic-add into d_out.

typedef __attribute__((ext_vector_type(8))) short bf16x8;
typedef __attribute__((ext_vector_type(4))) float f32x4;

__device__ __forceinline__ short f2bf(float f) {
  unsigned u = __builtin_bit_cast(unsigned, f);
  u += 0x7FFFu + ((u >> 16) & 1u);
  return (short)(u >> 16);
}

// ---------------- gate: logits (fp64), softmax, top-2, counts ----------------
__global__ __launch_bounds__(256) void gate_kernel(
    const float* __restrict__ x, const float* __restrict__ Wg,
    const float* __restrict__ bg, int* __restrict__ tok_e,
    float* __restrict__ tok_w, int* __restrict__ counts) {
  const int wave = threadIdx.x >> 6;
  const int lane = threadIdx.x & 63;
  const int t = blockIdx.x * 4 + wave;
  const float* xr = x + (size_t)t * 1024;
  double acc[8] = {0, 0, 0, 0, 0, 0, 0, 0};
  for (int i = 0; i < 16; ++i) {
    const int d = i * 64 + lane;
    const double xv = (double)xr[d];
    const float* wr = Wg + d * 8;
#pragma unroll
    for (int e = 0; e < 8; ++e) acc[e] += xv * (double)wr[e];
  }
#pragma unroll
  for (int e = 0; e < 8; ++e) {
    double v = acc[e];
#pragma unroll
    for (int off = 32; off > 0; off >>= 1) v += __shfl_xor(v, off, 64);
    acc[e] = v + (double)bg[e];
  }
  if (lane == 0) {
    int e0 = 0;
#pragma unroll
    for (int e = 1; e < 8; ++e)
      if (acc[e] > acc[e0]) e0 = e;
    int e1 = (e0 == 0) ? 1 : 0;
#pragma unroll
    for (int e = 0; e < 8; ++e) {
      if (e != e0 && acc[e] > acc[e1]) e1 = e;
    }
    const double m = acc[e0];
    double s = 0.0;
#pragma unroll
    for (int e = 0; e < 8; ++e) s += exp(acc[e] - m);
    const double p0 = exp(acc[e0] - m) / s;
    const double p1 = exp(acc[e1] - m) / s;
    const double den = p0 + p1 + 1e-9;
    tok_e[2 * t] = e0;
    tok_e[2 * t + 1] = e1;
    tok_w[2 * t] = (float)(p0 / den);
    tok_w[2 * t + 1] = (float)(p1 / den);
    atomicAdd(&counts[e0], 1);
    atomicAdd(&counts[e1], 1);
  }
}

// ---------------- prefix sums ----------------
__global__ void scan_kernel(const int* __restrict__ counts,
                            int* __restrict__ offsets,
                            int* __restrict__ cursors) {
  if (threadIdx.x == 0) {
    int s = 0;
    for (int e = 0; e < 8; ++e) {
      offsets[e] = s;
      cursors[e] = s;
      s += counts[e];
    }
  }
}

// ---------------- scatter tokens into per-expert buckets ----------------
__global__ __launch_bounds__(256) void scatter_kernel(
    const int* __restrict__ tok_e, const float* __restrict__ tok_w,
    int* __restrict__ cursors, int* __restrict__ pair_token,
    float* __restrict__ pair_w) {
  const int t = blockIdx.x * 256 + threadIdx.x;
  if (t >= 4096) return;
#pragma unroll
  for (int j = 0; j < 2; ++j) {
    const int e = tok_e[2 * t + j];
    const int slot = atomicAdd(&cursors[e], 1);
    pair_token[slot] = t;
    pair_w[slot] = tok_w[2 * t + j];
  }
}

// ---------------- GEMM1: H[slot, f] = relu(x[tok] @ W1[e] + b1[e]) ----------------
// 128x128 tile, BK=32, 4 waves (2x2), 16x16x32 bf16 MFMA.
__global__ __launch_bounds__(256) void gemm1_kernel(
    const float* __restrict__ x, const float* __restrict__ W1,
    const float* __restrict__ b1, const int* __restrict__ counts,
    const int* __restrict__ offsets, const int* __restrict__ pair_token,
    unsigned short* __restrict__ H, int f0, int FF_C) {
  const int e = blockIdx.z;
  const int count = counts[e];
  const int m0 = blockIdx.y * 128;
  if (m0 >= count) return;
  const int offset = offsets[e];
  const int n0 = blockIdx.x * 128;

  __shared__ __align__(16) short Blds[128][40];  // [n][k] bf16, 80B row stride
  __shared__ int toklds[128];

  const int tid = threadIdx.x;
  if (tid < 128) {
    int r = m0 + tid;
    if (r >= count) r = count - 1;
    toklds[tid] = pair_token[offset + r];
  }
  __syncthreads();

  const int lane = tid & 63;
  const int wave = tid >> 6;
  const int wm = (wave >> 1) * 64;
  const int wn = (wave & 1) * 64;
  const int l16 = lane & 15;
  const int lk = lane >> 4;

  const float* aptr[4];
#pragma unroll
  for (int mi = 0; mi < 4; ++mi) {
    const int tok = toklds[wm + mi * 16 + l16];
    aptr[mi] = x + (size_t)tok * 1024 + lk * 8;
  }

  const int kq = tid >> 5;  // 0..7 -> 4 k-rows each
  const int fb = tid & 31;  // column lane
  const float* wbase = W1 + (size_t)e * 1024 * 4096 + (size_t)(f0 + n0);

  f32x4 acc[4][4] = {};

  for (int kt = 0; kt < 1024; kt += 32) {
    if (kt) __syncthreads();
    // stage W1 tile transposed into LDS as bf16
#pragma unroll
    for (int j = 0; j < 4; ++j) {
      const int n = fb + j * 32;
      unsigned long long pk = 0;
#pragma unroll
      for (int r = 0; r < 4; ++r) {
        const float v = wbase[(size_t)(kt + kq * 4 + r) * 4096 + n];
        pk |= (unsigned long long)(unsigned short)f2bf(v) << (16 * r);
      }
      *(unsigned long long*)&Blds[n][kq * 4] = pk;
    }
    __syncthreads();

    bf16x8 af[4];
#pragma unroll
    for (int mi = 0; mi < 4; ++mi) {
      const float* p = aptr[mi] + kt;
      const float4 v0 = *(const float4*)p;
      const float4 v1 = *(const float4*)(p + 4);
      bf16x8 a;
      a[0] = f2bf(v0.x); a[1] = f2bf(v0.y); a[2] = f2bf(v0.z); a[3] = f2bf(v0.w);
      a[4] = f2bf(v1.x); a[5] = f2bf(v1.y); a[6] = f2bf(v1.z); a[7] = f2bf(v1.w);
      af[mi] = a;
    }
    bf16x8 bfr[4];
#pragma unroll
    for (int nj = 0; nj < 4; ++nj)
      bfr[nj] = *(const bf16x8*)&Blds[wn + nj * 16 + l16][lk * 8];
#pragma unroll
    for (int mi = 0; mi < 4; ++mi)
#pragma unroll
      for (int nj = 0; nj < 4; ++nj)
        acc[mi][nj] = __builtin_amdgcn_mfma_f32_16x16x32_bf16(
            af[mi], bfr[nj], acc[mi][nj], 0, 0, 0);
  }

  // epilogue: +b1, relu, bf16 -> H
#pragma unroll
  for (int mi = 0; mi < 4; ++mi) {
#pragma unroll
    for (int r = 0; r < 4; ++r) {
      const int rl = m0 + wm + mi * 16 + lk * 4 + r;
      if (rl >= count) continue;
      unsigned short* hrow = H + (size_t)(offset + rl) * FF_C;
#pragma unroll
      for (int nj = 0; nj < 4; ++nj) {
        const int c = n0 + wn + nj * 16 + l16;
        float v = acc[mi][nj][r] + b1[e * 4096 + f0 + c];
        v = v > 0.f ? v : 0.f;
        hrow[c] = (unsigned short)f2bf(v);
      }
    }
  }
}

// ---------------- GEMM2: out[tok] += w * (H @ W2[e] + b2[e]) ----------------
__global__ __launch_bounds__(256) void gemm2_kernel(
    const unsigned short* __restrict__ H, const float* __restrict__ W2,
    const float* __restrict__ b2, const int* __restrict__ counts,
    const int* __restrict__ offsets, const int* __restrict__ pair_token,
    const float* __restrict__ pair_w, float* __restrict__ out, int f0, int FF_C,
    int addBias) {
  const int e = blockIdx.z;
  const int count = counts[e];
  const int m0 = blockIdx.y * 128;
  if (m0 >= count) return;
  const int offset = offsets[e];
  const int n0 = blockIdx.x * 128;

  __shared__ __align__(16) short Blds[128][40];
  __shared__ int toklds[128];
  __shared__ float wlds[128];

  const int tid = threadIdx.x;
  if (tid < 128) {
    int r = m0 + tid;
    if (r >= count) r = count - 1;
    toklds[tid] = pair_token[offset + r];
    wlds[tid] = pair_w[offset + r];
  }
  __syncthreads();

  const int lane = tid & 63;
  const int wave = tid >> 6;
  const int wm = (wave >> 1) * 64;
  const int wn = (wave & 1) * 64;
  const int l16 = lane & 15;
  const int lk = lane >> 4;

  const unsigned short* aptr[4];
#pragma unroll
  for (int mi = 0; mi < 4; ++mi) {
    int rm = m0 + wm + mi * 16 + l16;
    if (rm >= count) rm = count - 1;
    aptr[mi] = H + (size_t)(offset + rm) * FF_C + lk * 8;
  }

  const int kq = tid >> 5;
  const int fb = tid & 31;
  const float* wbase = W2 + (size_t)e * 4096 * 1024 + (size_t)f0 * 1024 + n0;

  f32x4 acc[4][4] = {};

  for (int kt = 0; kt < FF_C; kt += 32) {
    if (kt) __syncthreads();
#pragma unroll
    for (int j = 0; j < 4; ++j) {
      const int n = fb + j * 32;
      unsigned long long pk = 0;
#pragma unroll
      for (int r = 0; r < 4; ++r) {
        const float v = wbase[(size_t)(kt + kq * 4 + r) * 1024 + n];
        pk |= (unsigned long long)(unsigned short)f2bf(v) << (16 * r);
      }
      *(unsigned long long*)&Blds[n][kq * 4] = pk;
    }
    __syncthreads();

    bf16x8 af[4];
#pragma unroll
    for (int mi = 0; mi < 4; ++mi) af[mi] = *(const bf16x8*)(aptr[mi] + kt);
    bf16x8 bfr[4];
#pragma unroll
    for (int nj = 0; nj < 4; ++nj)
      bfr[nj] = *(const bf16x8*)&Blds[wn + nj * 16 + l16][lk * 8];
#pragma unroll
    for (int mi = 0; mi < 4; ++mi)
#pragma unroll
      for (int nj = 0; nj < 4; ++nj)
        acc[mi][nj] = __builtin_amdgcn_mfma_f32_16x16x32_bf16(
            af[mi], bfr[nj], acc[mi][nj], 0, 0, 0);
  }

#pragma unroll
  for (int mi = 0; mi < 4; ++mi) {
#pragma unroll
    for (int r = 0; r < 4; ++r) {
      const int rloc = wm + mi * 16 + lk * 4 + r;
      const int rl = m0 + rloc;
      if (rl >= count) continue;
      const int tok = toklds[rloc];
      const float wgt = wlds[rloc];
      float* orow = out + (size_t)tok * 1024;
#pragma unroll
      for (int nj = 0; nj < 4; ++nj) {
        const int c = n0 + wn + nj * 16 + l16;
        float v = acc[mi][nj][r];
        if (addBias) v += b2[e * 1024 + c];
        unsafeAtomicAdd(&orow[c], v * wgt);
      }
    }
  }
}

extern "C" void kernel_launch(void* const* d_in, const int* in_sizes, int n_in,
                              void* d_out, int out_size, void* d_ws,
                              size_t ws_size, hipStream_t stream) {
  const float* x = (const float*)d_in[0];
  const float* Wg = (const float*)d_in[1];
  const float* bg = (const float*)d_in[2];
  const float* W1 = (const float*)d_in[3];
  const float* b1 = (const float*)d_in[4];
  const float* W2 = (const float*)d_in[5];
  const float* b2 = (const float*)d_in[6];
  float* out = (float*)d_out;

  char* w = (char*)d_ws;
  int* counts = (int*)(w + 0);
  int* offsets = (int*)(w + 64);
  int* cursors = (int*)(w + 128);
  int* tok_e = (int*)(w + 1024);
  float* tok_w = (float*)(w + 33792);
  int* pair_token = (int*)(w + 66560);
  float* pair_w = (float*)(w + 99328);
  unsigned short* Hbuf = (unsigned short*)(w + 147456);

  // FF chunk sized to fit workspace: H = 8192 * FF_C * 2 bytes
  int FF_C = 4096;
  while ((size_t)147456 + (size_t)8192 * FF_C * 2 > ws_size && FF_C > 128)
    FF_C >>= 1;

  hipMemsetAsync(counts, 0, 64, stream);
  hipMemsetAsync(d_out, 0, (size_t)out_size * 4, stream);

  gate_kernel<<<1024, 256, 0, stream>>>(x, Wg, bg, tok_e, tok_w, counts);
  scan_kernel<<<1, 64, 0, stream>>>(counts, offsets, cursors);
  scatter_kernel<<<16, 256, 0, stream>>>(tok_e, tok_w, cursors, pair_token,
                                         pair_w);

  for (int f0 = 0; f0 < 4096; f0 += FF_C) {
    gemm1_kernel<<<dim3(FF_C / 128, 32, 8), 256, 0, stream>>>(
        x, W1, b1, counts, offsets, pair_token, Hbuf, f0, FF_C);
    gemm2_kernel<<<dim3(8, 32, 8), 256, 0, stream>>>(
        Hbuf, W2, b2, counts, offsets, pair_token, pair_w, out, f0, FF_C,
        f0 == 0 ? 1 : 0);
  }
}

// Round 2
// 549.794 us; speedup vs baseline: 2.2653x; 2.2653x over previous
//
#include <hip/hip_runtime.h>
#include <hip/hip_bf16.h>

// SimpleMoE: B=2,S=2048 -> 4096 tokens, DIM=1024, FF=4096, E=8, top-2 routing.
// Round 2: pre-convert/transpose weights to bf16 K-contiguous layouts, then
// m97-structure grouped GEMMs (global_load_lds + ds_read_b128 + MFMA).

typedef __attribute__((ext_vector_type(8))) short bf16x8;
typedef __attribute__((ext_vector_type(4))) float f32x4;

__device__ __forceinline__ unsigned short f2bf(float f) {
  unsigned u = __builtin_bit_cast(unsigned, f);
  u += 0x7FFFu + ((u >> 16) & 1u);
  return (unsigned short)(u >> 16);
}

__device__ __forceinline__ void gload_lds16(const void* g, void* l) {
  __builtin_amdgcn_global_load_lds(
      (const __attribute__((address_space(1))) unsigned int*)g,
      (__attribute__((address_space(3))) unsigned int*)l, 16, 0, 0);
}

// ---------------- gate: logits (fp64), softmax, top-2, counts ----------------
__global__ __launch_bounds__(256) void gate_kernel(
    const float* __restrict__ x, const float* __restrict__ Wg,
    const float* __restrict__ bg, int* __restrict__ tok_e,
    float* __restrict__ tok_w, int* __restrict__ counts) {
  const int wave = threadIdx.x >> 6;
  const int lane = threadIdx.x & 63;
  const int t = blockIdx.x * 4 + wave;
  const float* xr = x + (size_t)t * 1024;
  double acc[8] = {0, 0, 0, 0, 0, 0, 0, 0};
  for (int i = 0; i < 16; ++i) {
    const int d = i * 64 + lane;
    const double xv = (double)xr[d];
    const float* wr = Wg + d * 8;
#pragma unroll
    for (int e = 0; e < 8; ++e) acc[e] += xv * (double)wr[e];
  }
#pragma unroll
  for (int e = 0; e < 8; ++e) {
    double v = acc[e];
#pragma unroll
    for (int off = 32; off > 0; off >>= 1) v += __shfl_xor(v, off, 64);
    acc[e] = v + (double)bg[e];
  }
  if (lane == 0) {
    int e0 = 0;
#pragma unroll
    for (int e = 1; e < 8; ++e)
      if (acc[e] > acc[e0]) e0 = e;
    int e1 = (e0 == 0) ? 1 : 0;
#pragma unroll
    for (int e = 0; e < 8; ++e) {
      if (e != e0 && acc[e] > acc[e1]) e1 = e;
    }
    const double m = acc[e0];
    double s = 0.0;
#pragma unroll
    for (int e = 0; e < 8; ++e) s += exp(acc[e] - m);
    const double p0 = exp(acc[e0] - m) / s;
    const double p1 = exp(acc[e1] - m) / s;
    const double den = p0 + p1 + 1e-9;
    tok_e[2 * t] = e0;
    tok_e[2 * t + 1] = e1;
    tok_w[2 * t] = (float)(p0 / den);
    tok_w[2 * t + 1] = (float)(p1 / den);
    atomicAdd(&counts[e0], 1);
    atomicAdd(&counts[e1], 1);
  }
}

__global__ void scan_kernel(const int* __restrict__ counts,
                            int* __restrict__ offsets,
                            int* __restrict__ cursors) {
  if (threadIdx.x == 0) {
    int s = 0;
    for (int e = 0; e < 8; ++e) {
      offsets[e] = s;
      cursors[e] = s;
      s += counts[e];
    }
  }
}

__global__ __launch_bounds__(256) void scatter_kernel(
    const int* __restrict__ tok_e, const float* __restrict__ tok_w,
    int* __restrict__ cursors, int* __restrict__ pair_token,
    float* __restrict__ pair_w) {
  const int t = blockIdx.x * 256 + threadIdx.x;
  if (t >= 4096) return;
#pragma unroll
  for (int j = 0; j < 2; ++j) {
    const int e = tok_e[2 * t + j];
    const int slot = atomicAdd(&cursors[e], 1);
    pair_token[slot] = t;
    pair_w[slot] = tok_w[2 * t + j];
  }
}

// ---------------- x -> bf16 ----------------
__global__ __launch_bounds__(256) void xconv_kernel(
    const float* __restrict__ x, unsigned short* __restrict__ xb) {
  const size_t i = ((size_t)blockIdx.x * 256 + threadIdx.x) * 4;
  const float4 v = *(const float4*)(x + i);
  ushort4 pk;
  pk.x = f2bf(v.x); pk.y = f2bf(v.y); pk.z = f2bf(v.z); pk.w = f2bf(v.w);
  *(ushort4*)(xb + i) = pk;
}

// ---------------- W1[e][k][f] -> W1t[e][f_local][k] (bf16) ----------------
// grid: (FC/64, 8, 8)  block 256
__global__ __launch_bounds__(256) void transW1_kernel(
    const float* __restrict__ W1, unsigned short* __restrict__ W1t, int FC,
    int f0) {
  const int e = blockIdx.z;
  const int fl = blockIdx.x * 64 + (threadIdx.x & 63);
  const int kg = threadIdx.x >> 6;
  const int kbase = (blockIdx.y * 4 + kg) * 32;
  const float* src = W1 + ((size_t)e * 1024 + kbase) * 4096 + f0 + fl;
  unsigned short* dst = W1t + ((size_t)e * FC + fl) * 1024 + kbase;
  for (int i = 0; i < 8; ++i) {
    ushort4 pk;
    pk.x = f2bf(src[(size_t)(i * 4 + 0) * 4096]);
    pk.y = f2bf(src[(size_t)(i * 4 + 1) * 4096]);
    pk.z = f2bf(src[(size_t)(i * 4 + 2) * 4096]);
    pk.w = f2bf(src[(size_t)(i * 4 + 3) * 4096]);
    *(ushort4*)&dst[i * 4] = pk;
  }
}

// ---------------- W2[e][f][d] -> W2t[e][d][f_local] (bf16) ----------------
// grid: (16, FC/128, 8)  block 256
__global__ __launch_bounds__(256) void transW2_kernel(
    const float* __restrict__ W2, unsigned short* __restrict__ W2t, int FC,
    int f0) {
  const int e = blockIdx.z;
  const int dl = blockIdx.x * 64 + (threadIdx.x & 63);
  const int fg = threadIdx.x >> 6;
  const int fbase = (blockIdx.y * 4 + fg) * 32;
  const float* src = W2 + ((size_t)e * 4096 + f0 + fbase) * 1024 + dl;
  unsigned short* dst = W2t + ((size_t)e * 1024 + dl) * FC + fbase;
  for (int i = 0; i < 8; ++i) {
    ushort4 pk;
    pk.x = f2bf(src[(size_t)(i * 4 + 0) * 1024]);
    pk.y = f2bf(src[(size_t)(i * 4 + 1) * 1024]);
    pk.z = f2bf(src[(size_t)(i * 4 + 2) * 1024]);
    pk.w = f2bf(src[(size_t)(i * 4 + 3) * 1024]);
    *(ushort4*)&dst[i * 4] = pk;
  }
}

// ---------------- GEMM1: H[slot][n] = relu(xb[tok] @ W1t[e] + b1) -----------
// m97 structure: 128x128 tile, BK=32, 4 waves 2x2, global_load_lds staging.
__global__ __launch_bounds__(256) void gemm1_kernel(
    const unsigned short* __restrict__ xb,
    const unsigned short* __restrict__ W1t, const float* __restrict__ b1,
    const int* __restrict__ counts, const int* __restrict__ offsets,
    const int* __restrict__ pair_token, unsigned short* __restrict__ H, int FC,
    int f0) {
  const int e = blockIdx.z;
  const int count = counts[e];
  const int m0 = blockIdx.y * 128;
  if (m0 >= count) return;
  const int offset = offsets[e];
  const int n0 = blockIdx.x * 128;

  __shared__ __align__(16) unsigned short Alds[128 * 32];
  __shared__ __align__(16) unsigned short Blds[128 * 32];
  __shared__ int toklds[128];

  const int tid = threadIdx.x;
  if (tid < 128) {
    int r = m0 + tid;
    if (r >= count) r = count - 1;
    toklds[tid] = pair_token[offset + r];
  }
  __syncthreads();

  const int lane = tid & 63;
  const int wave = tid >> 6;
  // staging: wave stages A rows [32w,32w+32) and B rows [32w,32w+32)
  // issue i covers 16 rows; lane -> row=lane>>2, kpart=(lane&3)*8 shorts
  const int srow = lane >> 2;
  const int skp = (lane & 3) * 8;
  const unsigned short* aga[2];
  const unsigned short* bga[2];
  unsigned short* alda[2];
  unsigned short* bldb[2];
#pragma unroll
  for (int i = 0; i < 2; ++i) {
    const int ar = wave * 32 + i * 16 + srow;
    aga[i] = xb + (size_t)toklds[ar] * 1024 + skp;
    bga[i] = W1t + ((size_t)e * FC + n0 + wave * 32 + i * 16 + srow) * 1024 + skp;
    alda[i] = Alds + (wave * 32 + i * 16) * 32;
    bldb[i] = Blds + (wave * 32 + i * 16) * 32;
  }

  const int wm = (wave >> 1) * 64;
  const int wn = (wave & 1) * 64;
  const int l16 = lane & 15;
  const int lk = lane >> 4;

  f32x4 acc[4][4] = {};

  for (int kt = 0; kt < 1024; kt += 32) {
    if (kt) __syncthreads();
#pragma unroll
    for (int i = 0; i < 2; ++i) {
      gload_lds16(aga[i] + kt, alda[i]);
      gload_lds16(bga[i] + kt, bldb[i]);
    }
    __syncthreads();  // drains vmcnt(0) + lgkmcnt(0)

    bf16x8 af[4], bfr[4];
#pragma unroll
    for (int mi = 0; mi < 4; ++mi)
      af[mi] = *(const bf16x8*)&Alds[(wm + mi * 16 + l16) * 32 + lk * 8];
#pragma unroll
    for (int nj = 0; nj < 4; ++nj)
      bfr[nj] = *(const bf16x8*)&Blds[(wn + nj * 16 + l16) * 32 + lk * 8];
#pragma unroll
    for (int mi = 0; mi < 4; ++mi)
#pragma unroll
      for (int nj = 0; nj < 4; ++nj)
        acc[mi][nj] = __builtin_amdgcn_mfma_f32_16x16x32_bf16(
            af[mi], bfr[nj], acc[mi][nj], 0, 0, 0);
  }

#pragma unroll
  for (int mi = 0; mi < 4; ++mi) {
#pragma unroll
    for (int r = 0; r < 4; ++r) {
      const int rl = m0 + wm + mi * 16 + lk * 4 + r;
      if (rl >= count) continue;
      unsigned short* hrow = H + (size_t)(offset + rl) * FC;
#pragma unroll
      for (int nj = 0; nj < 4; ++nj) {
        const int c = n0 + wn + nj * 16 + l16;
        float v = acc[mi][nj][r] + b1[e * 4096 + f0 + c];
        hrow[c] = f2bf(v > 0.f ? v : 0.f);
      }
    }
  }
}

// ---------------- GEMM2: out[tok] += w * (H @ W2t[e] + b2) ------------------
__global__ __launch_bounds__(256) void gemm2_kernel(
    const unsigned short* __restrict__ H,
    const unsigned short* __restrict__ W2t, const float* __restrict__ b2,
    const int* __restrict__ counts, const int* __restrict__ offsets,
    const int* __restrict__ pair_token, const float* __restrict__ pair_w,
    float* __restrict__ out, int FC, int addBias) {
  const int e = blockIdx.z;
  const int count = counts[e];
  const int m0 = blockIdx.y * 128;
  if (m0 >= count) return;
  const int offset = offsets[e];
  const int n0 = blockIdx.x * 128;

  __shared__ __align__(16) unsigned short Alds[128 * 32];
  __shared__ __align__(16) unsigned short Blds[128 * 32];
  __shared__ int toklds[128];
  __shared__ float wlds[128];

  const int tid = threadIdx.x;
  if (tid < 128) {
    int r = m0 + tid;
    if (r >= count) r = count - 1;
    toklds[tid] = pair_token[offset + r];
    wlds[tid] = pair_w[offset + r];
  }
  __syncthreads();

  const int lane = tid & 63;
  const int wave = tid >> 6;
  const int srow = lane >> 2;
  const int skp = (lane & 3) * 8;
  const unsigned short* aga[2];
  const unsigned short* bga[2];
  unsigned short* alda[2];
  unsigned short* bldb[2];
#pragma unroll
  for (int i = 0; i < 2; ++i) {
    int ar = m0 + wave * 32 + i * 16 + srow;
    if (ar >= count) ar = count - 1;
    aga[i] = H + (size_t)(offset + ar) * FC + skp;
    bga[i] = W2t + ((size_t)e * 1024 + n0 + wave * 32 + i * 16 + srow) * FC + skp;
    alda[i] = Alds + (wave * 32 + i * 16) * 32;
    bldb[i] = Blds + (wave * 32 + i * 16) * 32;
  }

  const int wm = (wave >> 1) * 64;
  const int wn = (wave & 1) * 64;
  const int l16 = lane & 15;
  const int lk = lane >> 4;

  f32x4 acc[4][4] = {};

  for (int kt = 0; kt < FC; kt += 32) {
    if (kt) __syncthreads();
#pragma unroll
    for (int i = 0; i < 2; ++i) {
      gload_lds16(aga[i] + kt, alda[i]);
      gload_lds16(bga[i] + kt, bldb[i]);
    }
    __syncthreads();

    bf16x8 af[4], bfr[4];
#pragma unroll
    for (int mi = 0; mi < 4; ++mi)
      af[mi] = *(const bf16x8*)&Alds[(wm + mi * 16 + l16) * 32 + lk * 8];
#pragma unroll
    for (int nj = 0; nj < 4; ++nj)
      bfr[nj] = *(const bf16x8*)&Blds[(wn + nj * 16 + l16) * 32 + lk * 8];
#pragma unroll
    for (int mi = 0; mi < 4; ++mi)
#pragma unroll
      for (int nj = 0; nj < 4; ++nj)
        acc[mi][nj] = __builtin_amdgcn_mfma_f32_16x16x32_bf16(
            af[mi], bfr[nj], acc[mi][nj], 0, 0, 0);
  }

#pragma unroll
  for (int mi = 0; mi < 4; ++mi) {
#pragma unroll
    for (int r = 0; r < 4; ++r) {
      const int rloc = wm + mi * 16 + lk * 4 + r;
      const int rl = m0 + rloc;
      if (rl >= count) continue;
      const int tok = toklds[rloc];
      const float wgt = wlds[rloc];
      float* orow = out + (size_t)tok * 1024;
#pragma unroll
      for (int nj = 0; nj < 4; ++nj) {
        const int c = n0 + wn + nj * 16 + l16;
        float v = acc[mi][nj][r];
        if (addBias) v += b2[e * 1024 + c];
        unsafeAtomicAdd(&orow[c], v * wgt);
      }
    }
  }
}

extern "C" void kernel_launch(void* const* d_in, const int* in_sizes, int n_in,
                              void* d_out, int out_size, void* d_ws,
                              size_t ws_size, hipStream_t stream) {
  const float* x = (const float*)d_in[0];
  const float* Wg = (const float*)d_in[1];
  const float* bg = (const float*)d_in[2];
  const float* W1 = (const float*)d_in[3];
  const float* b1 = (const float*)d_in[4];
  const float* W2 = (const float*)d_in[5];
  const float* b2 = (const float*)d_in[6];
  float* out = (float*)d_out;

  char* w = (char*)d_ws;
  int* counts = (int*)w;           // 64B
  int* offsets = counts + 16;      // @64
  int* cursors = counts + 32;      // @128
  int* tok_e = (int*)(w + 1024);               // 32KB
  float* tok_w = (float*)(w + 1024 + 32768);   // 32KB
  int* pair_token = (int*)(w + 1024 + 65536);  // 32KB
  float* pair_w = (float*)(w + 1024 + 98304);  // 32KB
  unsigned short* xb = (unsigned short*)(w + 256 * 1024);  // 8MB
  char* big = w + 256 * 1024 + 8 * 1024 * 1024;
  const size_t avail = ws_size - (256 * 1024 + 8 * 1024 * 1024);

  // per-chunk: W1t 16384*FC + W2t 16384*FC + H 16384*FC bytes
  int FC = 4096;
  while (FC > 256 && (size_t)FC * 49152 > avail) FC >>= 1;

  unsigned short* W1t = (unsigned short*)big;
  unsigned short* W2t = W1t + (size_t)8 * FC * 1024;
  unsigned short* Hc = W2t + (size_t)8 * 1024 * FC;

  hipMemsetAsync(counts, 0, 64, stream);
  hipMemsetAsync(d_out, 0, (size_t)out_size * 4, stream);

  gate_kernel<<<1024, 256, 0, stream>>>(x, Wg, bg, tok_e, tok_w, counts);
  scan_kernel<<<1, 64, 0, stream>>>(counts, offsets, cursors);
  scatter_kernel<<<16, 256, 0, stream>>>(tok_e, tok_w, cursors, pair_token,
                                         pair_w);
  xconv_kernel<<<4096, 256, 0, stream>>>(x, xb);

  for (int f0 = 0; f0 < 4096; f0 += FC) {
    transW1_kernel<<<dim3(FC / 64, 8, 8), 256, 0, stream>>>(W1, W1t, FC, f0);
    transW2_kernel<<<dim3(16, FC / 128, 8), 256, 0, stream>>>(W2, W2t, FC, f0);
    gemm1_kernel<<<dim3(FC / 128, 32, 8), 256, 0, stream>>>(
        xb, W1t, b1, counts, offsets, pair_token, Hc, FC, f0);
    gemm2_kernel<<<dim3(8, 32, 8), 256, 0, stream>>>(
        Hc, W2t, b2, counts, offsets, pair_token, pair_w, out, FC,
        f0 == 0 ? 1 : 0);
  }
}